// Round 18
// baseline (123.042 us; speedup 1.0000x reference)
//
#include <hip/hip_runtime.h>
#include <hip/hip_bf16.h>

#define BDIM 2
#define SDIM 2048
#define HDIM 16
#define DDIM 64
#define HID  1024
#define MDIM (BDIM * SDIM)  // 4096

typedef __attribute__((ext_vector_type(8))) short short8;
typedef __attribute__((ext_vector_type(4))) short short4v;
typedef __attribute__((ext_vector_type(4))) float f32x4;
typedef __attribute__((ext_vector_type(2))) unsigned int uint2v;

__device__ __forceinline__ float bf2f(short u) {
    union { unsigned int i; float f; } x;
    x.i = ((unsigned int)(unsigned short)u) << 16;
    return x.f;
}
__device__ __forceinline__ short f2bf(float f) {
    union { float f; unsigned int i; } x; x.f = f;
    unsigned int r = x.i + 0x7fffu + ((x.i >> 16) & 1u);
    return (short)(r >> 16);
}
__device__ __forceinline__ unsigned int cvtpk_bf16(float lo, float hi) {
    unsigned int r;
    asm("v_cvt_pk_bf16_f32 %0, %1, %2" : "=v"(r) : "v"(lo), "v"(hi));
    return r;
}
// barrier that does NOT drain vmcnt: own LDS ops complete (lgkmcnt0), then
// s_barrier. Global loads stay in flight across it (T4 counted-vmcnt idea);
// their consumers get compiler-emitted per-wave vmcnt waits instead of a
// block-wide drain at the barrier.
__device__ __forceinline__ void barrier_lds() {
    asm volatile("s_waitcnt lgkmcnt(0)" ::: "memory");
    __builtin_amdgcn_s_barrier();
    asm volatile("" ::: "memory");
}
// swizzled short-index into a [rows][64 shorts] tile; c8 = 16B chunk (0..7)
__device__ __forceinline__ int swz(int row, int c8) {
    return row * 64 + ((c8 ^ (row & 7)) << 3);
}

// ---------------- convert f32 -> bf16 (8 elems/thread) ----------------
__global__ __launch_bounds__(256) void cvt_bf16(const float* __restrict__ in,
                                               short* __restrict__ out, int n) {
    int i = (blockIdx.x * 256 + threadIdx.x) * 8;
    if (i >= n) return;
    float4 a = *(const float4*)(in + i);
    float4 b = *(const float4*)(in + i + 4);
    short8 v;
    v[0] = f2bf(a.x); v[1] = f2bf(a.y); v[2] = f2bf(a.z); v[3] = f2bf(a.w);
    v[4] = f2bf(b.x); v[5] = f2bf(b.y); v[6] = f2bf(b.z); v[7] = f2bf(b.w);
    *(short8*)(out + i) = v;
}

// ------------- transpose 4 f32 weights [K][N] -> bf16 [N][K] -------------
__global__ __launch_bounds__(256) void transpose4(
    const float* __restrict__ w0, const float* __restrict__ w1,
    const float* __restrict__ w2, const float* __restrict__ w3,
    short* __restrict__ o0, short* __restrict__ o1,
    short* __restrict__ o2, short* __restrict__ o3)
{
    const float* src; short* dst;
    int z = blockIdx.z;
    if (z == 0)      { src = w0; dst = o0; }
    else if (z == 1) { src = w1; dst = o1; }
    else if (z == 2) { src = w2; dst = o2; }
    else             { src = w3; dst = o3; }
    __shared__ float t[64][65];
    int r0 = blockIdx.y * 64, c0 = blockIdx.x * 64;
    int rd_r = threadIdx.x >> 4, rd_c = (threadIdx.x & 15) * 4;
    #pragma unroll
    for (int it = 0; it < 4; it++) {
        int rr = rd_r + it * 16;
        float4 v = *(const float4*)(src + (size_t)(r0 + rr) * HID + c0 + rd_c);
        t[rr][rd_c + 0] = v.x; t[rr][rd_c + 1] = v.y;
        t[rr][rd_c + 2] = v.z; t[rr][rd_c + 3] = v.w;
    }
    __syncthreads();
    int or_ = threadIdx.x >> 3, oc8 = (threadIdx.x & 7) * 8;
    #pragma unroll
    for (int half = 0; half < 2; half++) {
        int dr = or_ + half * 32;
        short8 v;
        #pragma unroll
        for (int i = 0; i < 8; i++) v[i] = f2bf(t[oc8 + i][dr]);
        *(short8*)(dst + (size_t)(c0 + dr) * HID + r0 + oc8) = v;
    }
}

// ------- GEMM, 2-phase double-buffered reg-staging (1 barrier/K-step) -------
// out = X[M,1024](bf16) @ Wt(bf16,[N][K]) + bias(f32)
// mode 0/1: q/k + RoPE -> [B,H,S,D]; mode 2: v -> V^T [B,H,D,S]; mode 3: f32 [M,N]
// Barrier is lgkmcnt-only: global prefetch loads stay in flight across it.
__global__ __launch_bounds__(256) void gemm_bf16(
    const short* __restrict__ X,
    const short* __restrict__ Wt0,
    const float* __restrict__ b0, const float* __restrict__ b1, const float* __restrict__ b2,
    const float* __restrict__ cosb, const float* __restrict__ sinb,
    short* __restrict__ out0, float* __restrict__ outf,
    int modeBase)
{
    constexpr int LDK = 40;  // 80B row stride: conflict-free fragment reads
    __shared__ __align__(16) short Asm[2][128 * LDK];
    __shared__ __align__(16) short Bsm[2][128 * LDK];
    int z = blockIdx.z;
    int mode = modeBase + z;
    const short* Wt = Wt0 + (size_t)z * HID * HID;
    const float* bias = (z == 0) ? b0 : (z == 1) ? b1 : b2;
    short* outp = out0 + (size_t)z * MDIM * HID;

    int tid = threadIdx.x;
    int lane = tid & 63, wave = tid >> 6;
    int wr = wave >> 1, wc = wave & 1;
    int m0 = blockIdx.x * 128, n0 = blockIdx.y * 128;
    int sr = tid >> 2, sc = (tid & 3) * 8;
    int lr = lane & 15, lg = lane >> 4;

    const short* ax = X  + (size_t)(m0 + sr) * HID + sc;
    const short* bx = Wt + (size_t)(n0 + sr) * HID + sc;
    int wA = sr * LDK + sc, wA2 = (sr + 64) * LDK + sc;

    f32x4 acc[4][4] = {};
    constexpr int NK = HID / 32;  // 32 K-steps

    short8 a0, a1, b0v, b1v;
    // prologue: k=0 -> buf0, k=1 -> regs
    a0  = *(const short8*)(ax);
    a1  = *(const short8*)(ax + (size_t)64 * HID);
    b0v = *(const short8*)(bx);
    b1v = *(const short8*)(bx + (size_t)64 * HID);
    *(short8*)(Asm[0] + wA)  = a0;
    *(short8*)(Asm[0] + wA2) = a1;
    *(short8*)(Bsm[0] + wA)  = b0v;
    *(short8*)(Bsm[0] + wA2) = b1v;
    a0  = *(const short8*)(ax + 32);
    a1  = *(const short8*)(ax + (size_t)64 * HID + 32);
    b0v = *(const short8*)(bx + 32);
    b1v = *(const short8*)(bx + (size_t)64 * HID + 32);

    int cur = 0;
    for (int ki = 0; ki < NK; ki++) {
        barrier_lds();       // buf[cur] ready; buf[cur^1] free; vmcnt NOT drained
        if (ki + 1 < NK) {   // stage next tile into other buffer
            *(short8*)(Asm[cur ^ 1] + wA)  = a0;
            *(short8*)(Asm[cur ^ 1] + wA2) = a1;
            *(short8*)(Bsm[cur ^ 1] + wA)  = b0v;
            *(short8*)(Bsm[cur ^ 1] + wA2) = b1v;
        }
        if (ki + 2 < NK) {   // T14: issue loads 2 steps ahead
            int k0 = (ki + 2) * 32;
            a0  = *(const short8*)(ax + k0);
            a1  = *(const short8*)(ax + (size_t)64 * HID + k0);
            b0v = *(const short8*)(bx + k0);
            b1v = *(const short8*)(bx + (size_t)64 * HID + k0);
        }
        short8 af[4], bfr[4];
        #pragma unroll
        for (int m = 0; m < 4; m++)
            af[m] = *(const short8*)(Asm[cur] + (wr * 64 + m * 16 + lr) * LDK + lg * 8);
        #pragma unroll
        for (int n = 0; n < 4; n++)
            bfr[n] = *(const short8*)(Bsm[cur] + (wc * 64 + n * 16 + lr) * LDK + lg * 8);
        __builtin_amdgcn_s_setprio(1);
        #pragma unroll
        for (int m = 0; m < 4; m++)
            #pragma unroll
            for (int n = 0; n < 4; n++)
                acc[m][n] = __builtin_amdgcn_mfma_f32_16x16x32_bf16(af[m], bfr[n], acc[m][n], 0, 0, 0);
        __builtin_amdgcn_s_setprio(0);
        cur ^= 1;
    }

    #pragma unroll
    for (int m = 0; m < 4; m++) {
        #pragma unroll
        for (int n = 0; n < 4; n++) {
            int gr0 = m0 + wr * 64 + m * 16 + lg * 4;
            int gc  = n0 + wc * 64 + n * 16 + lr;
            if (mode == 3) {
                #pragma unroll
                for (int j = 0; j < 4; j++)
                    outf[(size_t)(gr0 + j) * HID + gc] = acc[m][n][j] + bias[gc];
            } else if (mode == 2) {
                int bb = gr0 >> 11, s0 = gr0 & (SDIM - 1);
                int h = gc >> 6, dd = gc & 63;
                short4v pk;
                #pragma unroll
                for (int j = 0; j < 4; j++) pk[j] = f2bf(acc[m][n][j] + bias[gc]);
                *(short4v*)(outp + ((size_t)((bb * HDIM + h) * DDIM + dd)) * SDIM + s0) = pk;
            } else {
                #pragma unroll
                for (int j = 0; j < 4; j++) {
                    int gr = gr0 + j;
                    int bb = gr >> 11, s = gr & (SDIM - 1);
                    int h = gc >> 6, dd = gc & 63;
                    float v = acc[m][n][j] + bias[gc];
                    float p  = __shfl_xor(v, 1);
                    float cc = cosb[s * 32 + (dd >> 1)];
                    float ss = sinb[s * 32 + (dd >> 1)];
                    v = (dd & 1) ? (p * ss + v * cc) : (v * cc - p * ss);
                    outp[((size_t)((bb * HDIM + h) * SDIM + s)) * DDIM + dd] = f2bf(v);
                }
            }
        }
    }
}

// ------- causal flash attention: 8-wave blocks, maxless softmax -------
// Same lgkmcnt-only barrier: K/V prefetch loads stay in flight.
__global__ __launch_bounds__(512) void attn_fwd(
    const short* __restrict__ Q,
    const short* __restrict__ K,
    const short* __restrict__ Vt,
    short* __restrict__ O)
{
    __shared__ __align__(16) short Ks0[64 * 64], Ks1[64 * 64];
    __shared__ __align__(16) short Vs0[64 * 64], Vs1[64 * 64];
    __shared__ __align__(16) short Ps[8][16 * 64];
    int bx = blockIdx.x;                  // 0..15
    int qA = bx, qB = 31 - bx;            // qA < qB
    int bh = blockIdx.y;
    int tid = threadIdx.x;
    int lane = tid & 63, wave = tid >> 6;  // wave 0..7
    int wv = wave & 3, grp = wave >> 2;    // grp 0 -> qB, grp 1 -> qA
    int lr = lane & 15, lg = lane >> 4;
    const short* qbase  = Q  + ((size_t)bh * SDIM) * DDIM;
    const short* kbase  = K  + ((size_t)bh * SDIM) * DDIM;
    const short* vtbase = Vt + ((size_t)bh * DDIM) * SDIM;

    const float SCALE = 0.125f * 1.44269504088896340736f;  // 1/sqrt(64) * log2(e)

    int qt_own = grp ? qA : qB;
    int qrow = qt_own * 64 + wv * 16 + lr;

    short8 qf[2];
    #pragma unroll
    for (int ks = 0; ks < 2; ks++) {
        short8 a = *(const short8*)(qbase + (size_t)qrow * DDIM + ks * 32 + lg * 8);
        short8 ra;
        #pragma unroll
        for (int i = 0; i < 8; i++) ra[i] = f2bf(bf2f(a[i]) * SCALE);
        qf[ks] = ra;
    }

    f32x4 lacc = {0.f, 0.f, 0.f, 0.f};
    f32x4 oacc[4] = {};

    int sr_ = tid >> 3, sc8 = tid & 7;
    int kw = swz(sr_, sc8);
    int fo[8];
    #pragma unroll
    for (int ks = 0; ks < 2; ks++)
        #pragma unroll
        for (int n = 0; n < 4; n++) fo[ks * 4 + n] = swz(n * 16 + lr, ks * 4 + lg);
    int po[2] = { swz(lr, lg), swz(lr, 4 + lg) };
    int pw[4];
    #pragma unroll
    for (int n = 0; n < 4; n++)
        pw[n] = lr * 64 + (((n * 2 + (lg >> 1)) ^ (lr & 7)) << 3) + (lg & 1) * 4;

    int nt = qB + 1;  // >= 17

    short8 kreg, vreg;
    kreg = *(const short8*)(kbase + (size_t)sr_ * DDIM + sc8 * 8);
    vreg = *(const short8*)(vtbase + (size_t)sr_ * SDIM + sc8 * 8);
    *(short8*)(Ks0 + kw) = kreg;
    *(short8*)(Vs0 + kw) = vreg;
    kreg = *(const short8*)(kbase + (size_t)(64 + sr_) * DDIM + sc8 * 8);
    vreg = *(const short8*)(vtbase + (size_t)sr_ * SDIM + 64 + sc8 * 8);
    const short* kpre = kbase + (size_t)(128 + sr_) * DDIM + sc8 * 8;
    const short* vpre = vtbase + (size_t)sr_ * SDIM + 128 + sc8 * 8;

    auto pv = [&](f32x4 (&st)[4], bool diag, int kt, short* VsC) {
        if (diag) {
            #pragma unroll
            for (int n = 0; n < 4; n++)
                #pragma unroll
                for (int j = 0; j < 4; j++) {
                    int k = kt * 64 + n * 16 + lg * 4 + j;
                    if (k > qrow) st[n][j] = -1e30f;
                }
        }
        #pragma unroll
        for (int n = 0; n < 4; n++) {
            #pragma unroll
            for (int j = 0; j < 4; j++) st[n][j] = exp2f(st[n][j]);
            lacc[n] += (st[n][0] + st[n][1]) + (st[n][2] + st[n][3]);
        }
        #pragma unroll
        for (int n = 0; n < 4; n++) {
            uint2v pk;
            pk[0] = cvtpk_bf16(st[n][0], st[n][1]);
            pk[1] = cvtpk_bf16(st[n][2], st[n][3]);
            *(uint2v*)(Ps[wave] + pw[n]) = pk;
        }
        __builtin_amdgcn_s_setprio(1);
        #pragma unroll
        for (int ks = 0; ks < 2; ks++) {
            short8 pf = *(const short8*)(Ps[wave] + po[ks]);
            #pragma unroll
            for (int n = 0; n < 4; n++) {
                short8 vf = *(const short8*)(VsC + fo[ks * 4 + n]);
                oacc[n] = __builtin_amdgcn_mfma_f32_16x16x32_bf16(pf, vf, oacc[n], 0, 0, 0);
            }
        }
        __builtin_amdgcn_s_setprio(0);
    };

    auto tile = [&](int kt, short* KsC, short* VsC, short* KsN, short* VsN) {
        barrier_lds();                        // vmcnt NOT drained
        if (kt + 1 < nt) {
            *(short8*)(KsN + kw) = kreg;
            *(short8*)(VsN + kw) = vreg;
        }
        if (kt + 2 < nt) {
            kreg = *(const short8*)(kpre);
            vreg = *(const short8*)(vpre);
        }
        kpre += 64 * DDIM;
        vpre += 64;

        bool act = grp ? (kt <= qA) : true;
        if (act) {
            f32x4 st[4] = {};
            __builtin_amdgcn_s_setprio(1);
            #pragma unroll
            for (int ks = 0; ks < 2; ks++) {
                short8 kf[4];
                #pragma unroll
                for (int n = 0; n < 4; n++) kf[n] = *(const short8*)(KsC + fo[ks * 4 + n]);
                #pragma unroll
                for (int n = 0; n < 4; n++)
                    st[n] = __builtin_amdgcn_mfma_f32_16x16x32_bf16(kf[n], qf[ks], st[n], 0, 0, 0);
            }
            __builtin_amdgcn_s_setprio(0);
            pv(st, kt == qt_own, kt, VsC);
        }
    };

    for (int kt = 0; kt < nt; kt += 2) {
        tile(kt, Ks0, Vs0, Ks1, Vs1);
        if (kt + 1 < nt) tile(kt + 1, Ks1, Vs1, Ks0, Vs0);
    }

    float l = (lacc[0] + lacc[1]) + (lacc[2] + lacc[3]);
    l += __shfl_xor(l, 16);
    l += __shfl_xor(l, 32);
    int b = bh >> 4, h = bh & 15;
    float linv[4];
    #pragma unroll
    for (int j = 0; j < 4; j++)
        linv[j] = 1.f / __int_as_float(__builtin_amdgcn_ds_bpermute((lg * 4 + j) * 4, __float_as_int(l)));
    #pragma unroll
    for (int n = 0; n < 4; n++)
        #pragma unroll
        for (int j = 0; j < 4; j++) {
            int s = qt_own * 64 + wv * 16 + lg * 4 + j;
            int dd = n * 16 + lr;
            O[(((size_t)(b * SDIM + s) * HDIM) + h) * DDIM + dd] = f2bf(oacc[n][j] * linv[j]);
        }
}

extern "C" void kernel_launch(void* const* d_in, const int* in_sizes, int n_in,
                              void* d_out, int out_size, void* d_ws, size_t ws_size,
                              hipStream_t stream) {
    const float* x  = (const float*)d_in[0];
    const float* Wq = (const float*)d_in[1];
    const float* bq = (const float*)d_in[2];
    const float* Wk = (const float*)d_in[3];
    const float* bk = (const float*)d_in[4];
    const float* Wv = (const float*)d_in[5];
    const float* bv = (const float*)d_in[6];
    const float* Wo = (const float*)d_in[7];
    const float* bo = (const float*)d_in[8];
    const float* fc = (const float*)d_in[10];
    const float* fs = (const float*)d_in[11];
    float* out = (float*)d_out;
    short* ws  = (short*)d_ws;

    const size_t MM = (size_t)HID * HID;
    short* xb     = ws;
    short* wt_qkv = ws + 4 * MM;
    short* wot    = ws + 7 * MM;
    short* qt     = ws + 8 * MM;
    short* ktb    = ws + 12 * MM;
    short* vtb    = ws + 16 * MM;   // [B,H,D,S]
    short* ao     = ws + 20 * MM;

    cvt_bf16<<<dim3((MDIM * HID) / (256 * 8)), 256, 0, stream>>>(x, xb, MDIM * HID);
    transpose4<<<dim3(16, 16, 4), 256, 0, stream>>>(Wq, Wk, Wv, Wo,
                                                    wt_qkv, wt_qkv + MM, wt_qkv + 2 * MM, wot);
    gemm_bf16<<<dim3(MDIM / 128, HID / 128, 3), 256, 0, stream>>>(
        xb, wt_qkv, bq, bk, bv, fc, fs, qt, nullptr, 0);
    attn_fwd<<<dim3(16, BDIM * HDIM), 512, 0, stream>>>(qt, ktb, vtb, ao);
    gemm_bf16<<<dim3(MDIM / 128, HID / 128, 1), 256, 0, stream>>>(
        ao, wot, bo, bo, bo, fc, fs, nullptr, out, 3);
}

// Round 19
// 108.482 us; speedup vs baseline: 1.1342x; 1.1342x over previous
//
#include <hip/hip_runtime.h>
#include <hip/hip_bf16.h>

#define BDIM 2
#define SDIM 2048
#define HDIM 16
#define DDIM 64
#define HID  1024
#define MDIM (BDIM * SDIM)  // 4096

typedef __attribute__((ext_vector_type(8))) short short8;
typedef __attribute__((ext_vector_type(4))) short short4v;
typedef __attribute__((ext_vector_type(4))) float f32x4;
typedef __attribute__((ext_vector_type(2))) unsigned int uint2v;

__device__ __forceinline__ float bf2f(short u) {
    union { unsigned int i; float f; } x;
    x.i = ((unsigned int)(unsigned short)u) << 16;
    return x.f;
}
__device__ __forceinline__ short f2bf(float f) {
    union { float f; unsigned int i; } x; x.f = f;
    unsigned int r = x.i + 0x7fffu + ((x.i >> 16) & 1u);
    return (short)(r >> 16);
}
__device__ __forceinline__ unsigned int cvtpk_bf16(float lo, float hi) {
    unsigned int r;
    asm("v_cvt_pk_bf16_f32 %0, %1, %2" : "=v"(r) : "v"(lo), "v"(hi));
    return r;
}
// swizzled short-index into a [rows][64 shorts] tile; c8 = 16B chunk (0..7)
__device__ __forceinline__ int swz(int row, int c8) {
    return row * 64 + ((c8 ^ (row & 7)) << 3);
}

// ---------------- convert f32 -> bf16 (8 elems/thread) ----------------
__global__ __launch_bounds__(256) void cvt_bf16(const float* __restrict__ in,
                                               short* __restrict__ out, int n) {
    int i = (blockIdx.x * 256 + threadIdx.x) * 8;
    if (i >= n) return;
    float4 a = *(const float4*)(in + i);
    float4 b = *(const float4*)(in + i + 4);
    short8 v;
    v[0] = f2bf(a.x); v[1] = f2bf(a.y); v[2] = f2bf(a.z); v[3] = f2bf(a.w);
    v[4] = f2bf(b.x); v[5] = f2bf(b.y); v[6] = f2bf(b.z); v[7] = f2bf(b.w);
    *(short8*)(out + i) = v;
}

// ------------- transpose 4 f32 weights [K][N] -> bf16 [N][K] -------------
__global__ __launch_bounds__(256) void transpose4(
    const float* __restrict__ w0, const float* __restrict__ w1,
    const float* __restrict__ w2, const float* __restrict__ w3,
    short* __restrict__ o0, short* __restrict__ o1,
    short* __restrict__ o2, short* __restrict__ o3)
{
    const float* src; short* dst;
    int z = blockIdx.z;
    if (z == 0)      { src = w0; dst = o0; }
    else if (z == 1) { src = w1; dst = o1; }
    else if (z == 2) { src = w2; dst = o2; }
    else             { src = w3; dst = o3; }
    __shared__ float t[64][65];
    int r0 = blockIdx.y * 64, c0 = blockIdx.x * 64;
    int rd_r = threadIdx.x >> 4, rd_c = (threadIdx.x & 15) * 4;
    #pragma unroll
    for (int it = 0; it < 4; it++) {
        int rr = rd_r + it * 16;
        float4 v = *(const float4*)(src + (size_t)(r0 + rr) * HID + c0 + rd_c);
        t[rr][rd_c + 0] = v.x; t[rr][rd_c + 1] = v.y;
        t[rr][rd_c + 2] = v.z; t[rr][rd_c + 3] = v.w;
    }
    __syncthreads();
    int or_ = threadIdx.x >> 3, oc8 = (threadIdx.x & 7) * 8;
    #pragma unroll
    for (int half = 0; half < 2; half++) {
        int dr = or_ + half * 32;
        short8 v;
        #pragma unroll
        for (int i = 0; i < 8; i++) v[i] = f2bf(t[oc8 + i][dr]);
        *(short8*)(dst + (size_t)(c0 + dr) * HID + r0 + oc8) = v;
    }
}

// ------- GEMM, 2-phase double-buffered reg-staging (1 barrier/K-step) -------
// out = X[M,1024](bf16) @ Wt(bf16,[N][K]) + bias(f32)
// mode 0/1: q/k + RoPE -> [B,H,S,D]; mode 2: v -> V^T [B,H,D,S]; mode 3: f32 [M,N]
// LDS [128][32] shorts, XOR swizzle chunk^=(row>>1)&3 on write AND read:
// 2-way banks both sides (free, m136). 32KB LDS -> 4 blocks/CU (was 3 at 40KB).
__global__ __launch_bounds__(256) void gemm_bf16(
    const short* __restrict__ X,
    const short* __restrict__ Wt0,
    const float* __restrict__ b0, const float* __restrict__ b1, const float* __restrict__ b2,
    const float* __restrict__ cosb, const float* __restrict__ sinb,
    short* __restrict__ out0, float* __restrict__ outf,
    int modeBase)
{
    __shared__ __align__(16) short Asm[2][128 * 32];   // 16 KB
    __shared__ __align__(16) short Bsm[2][128 * 32];   // 16 KB
    int z = blockIdx.z;
    int mode = modeBase + z;
    const short* Wt = Wt0 + (size_t)z * HID * HID;
    const float* bias = (z == 0) ? b0 : (z == 1) ? b1 : b2;
    short* outp = out0 + (size_t)z * MDIM * HID;

    int tid = threadIdx.x;
    int lane = tid & 63, wave = tid >> 6;
    int wr = wave >> 1, wc = wave & 1;
    int m0 = blockIdx.x * 128, n0 = blockIdx.y * 128;
    int sr = tid >> 2, sc = (tid & 3) * 8;
    int lr = lane & 15, lg = lane >> 4;

    const short* ax = X  + (size_t)(m0 + sr) * HID + sc;
    const short* bx = Wt + (size_t)(n0 + sr) * HID + sc;
    // swizzled write offsets: phys chunk = (tid&3) ^ ((row>>1)&3); rows sr and
    // sr+64 share the field ((sr+64)>>1)&3 == (sr>>1)&3 since 64>>1=32 ≡ 0 mod 4
    int csw = ((tid & 3) ^ ((sr >> 1) & 3)) * 8;
    int wA  = sr * 32 + csw, wA2 = (sr + 64) * 32 + csw;
    // swizzled read offset: logical chunk lg at row m*16+lr -> phys lg^((lr>>1)&3)
    int rdsw = (lg ^ ((lr >> 1) & 3)) * 8;

    f32x4 acc[4][4] = {};
    constexpr int NK = HID / 32;  // 32 K-steps

    short8 a0, a1, b0v, b1v;
    // prologue: k=0 -> buf0, k=1 -> regs
    a0  = *(const short8*)(ax);
    a1  = *(const short8*)(ax + (size_t)64 * HID);
    b0v = *(const short8*)(bx);
    b1v = *(const short8*)(bx + (size_t)64 * HID);
    *(short8*)(Asm[0] + wA)  = a0;
    *(short8*)(Asm[0] + wA2) = a1;
    *(short8*)(Bsm[0] + wA)  = b0v;
    *(short8*)(Bsm[0] + wA2) = b1v;
    a0  = *(const short8*)(ax + 32);
    a1  = *(const short8*)(ax + (size_t)64 * HID + 32);
    b0v = *(const short8*)(bx + 32);
    b1v = *(const short8*)(bx + (size_t)64 * HID + 32);

    int cur = 0;
    for (int ki = 0; ki < NK; ki++) {
        __syncthreads();     // buf[cur] ready; buf[cur^1] free
        if (ki + 1 < NK) {   // stage next tile into other buffer
            *(short8*)(Asm[cur ^ 1] + wA)  = a0;
            *(short8*)(Asm[cur ^ 1] + wA2) = a1;
            *(short8*)(Bsm[cur ^ 1] + wA)  = b0v;
            *(short8*)(Bsm[cur ^ 1] + wA2) = b1v;
        }
        if (ki + 2 < NK) {   // T14: issue loads 2 steps ahead
            int k0 = (ki + 2) * 32;
            a0  = *(const short8*)(ax + k0);
            a1  = *(const short8*)(ax + (size_t)64 * HID + k0);
            b0v = *(const short8*)(bx + k0);
            b1v = *(const short8*)(bx + (size_t)64 * HID + k0);
        }
        short8 af[4], bfr[4];
        #pragma unroll
        for (int m = 0; m < 4; m++)
            af[m] = *(const short8*)(Asm[cur] + (wr * 64 + m * 16 + lr) * 32 + rdsw);
        #pragma unroll
        for (int n = 0; n < 4; n++)
            bfr[n] = *(const short8*)(Bsm[cur] + (wc * 64 + n * 16 + lr) * 32 + rdsw);
        __builtin_amdgcn_s_setprio(1);
        #pragma unroll
        for (int m = 0; m < 4; m++)
            #pragma unroll
            for (int n = 0; n < 4; n++)
                acc[m][n] = __builtin_amdgcn_mfma_f32_16x16x32_bf16(af[m], bfr[n], acc[m][n], 0, 0, 0);
        __builtin_amdgcn_s_setprio(0);
        cur ^= 1;
    }

    #pragma unroll
    for (int m = 0; m < 4; m++) {
        #pragma unroll
        for (int n = 0; n < 4; n++) {
            int gr0 = m0 + wr * 64 + m * 16 + lg * 4;
            int gc  = n0 + wc * 64 + n * 16 + lr;
            if (mode == 3) {
                #pragma unroll
                for (int j = 0; j < 4; j++)
                    outf[(size_t)(gr0 + j) * HID + gc] = acc[m][n][j] + bias[gc];
            } else if (mode == 2) {
                int bb = gr0 >> 11, s0 = gr0 & (SDIM - 1);
                int h = gc >> 6, dd = gc & 63;
                short4v pk;
                #pragma unroll
                for (int j = 0; j < 4; j++) pk[j] = f2bf(acc[m][n][j] + bias[gc]);
                *(short4v*)(outp + ((size_t)((bb * HDIM + h) * DDIM + dd)) * SDIM + s0) = pk;
            } else {
                #pragma unroll
                for (int j = 0; j < 4; j++) {
                    int gr = gr0 + j;
                    int bb = gr >> 11, s = gr & (SDIM - 1);
                    int h = gc >> 6, dd = gc & 63;
                    float v = acc[m][n][j] + bias[gc];
                    float p  = __shfl_xor(v, 1);
                    float cc = cosb[s * 32 + (dd >> 1)];
                    float ss = sinb[s * 32 + (dd >> 1)];
                    v = (dd & 1) ? (p * ss + v * cc) : (v * cc - p * ss);
                    outp[((size_t)((bb * HDIM + h) * SDIM + s)) * DDIM + dd] = f2bf(v);
                }
            }
        }
    }
}

// ------- causal flash attention: 8-wave blocks, maxless softmax -------
// (unchanged from R10/R17 — best measured attn)
__global__ __launch_bounds__(512) void attn_fwd(
    const short* __restrict__ Q,
    const short* __restrict__ K,
    const short* __restrict__ Vt,
    short* __restrict__ O)
{
    __shared__ __align__(16) short Ks0[64 * 64], Ks1[64 * 64];
    __shared__ __align__(16) short Vs0[64 * 64], Vs1[64 * 64];
    __shared__ __align__(16) short Ps[8][16 * 64];
    int bx = blockIdx.x;                  // 0..15
    int qA = bx, qB = 31 - bx;            // qA < qB
    int bh = blockIdx.y;
    int tid = threadIdx.x;
    int lane = tid & 63, wave = tid >> 6;  // wave 0..7
    int wv = wave & 3, grp = wave >> 2;    // grp 0 -> qB, grp 1 -> qA
    int lr = lane & 15, lg = lane >> 4;
    const short* qbase  = Q  + ((size_t)bh * SDIM) * DDIM;
    const short* kbase  = K  + ((size_t)bh * SDIM) * DDIM;
    const short* vtbase = Vt + ((size_t)bh * DDIM) * SDIM;

    const float SCALE = 0.125f * 1.44269504088896340736f;  // 1/sqrt(64) * log2(e)

    int qt_own = grp ? qA : qB;
    int qrow = qt_own * 64 + wv * 16 + lr;

    short8 qf[2];
    #pragma unroll
    for (int ks = 0; ks < 2; ks++) {
        short8 a = *(const short8*)(qbase + (size_t)qrow * DDIM + ks * 32 + lg * 8);
        short8 ra;
        #pragma unroll
        for (int i = 0; i < 8; i++) ra[i] = f2bf(bf2f(a[i]) * SCALE);
        qf[ks] = ra;
    }

    f32x4 lacc = {0.f, 0.f, 0.f, 0.f};
    f32x4 oacc[4] = {};

    int sr_ = tid >> 3, sc8 = tid & 7;
    int kw = swz(sr_, sc8);
    int fo[8];
    #pragma unroll
    for (int ks = 0; ks < 2; ks++)
        #pragma unroll
        for (int n = 0; n < 4; n++) fo[ks * 4 + n] = swz(n * 16 + lr, ks * 4 + lg);
    int po[2] = { swz(lr, lg), swz(lr, 4 + lg) };
    int pw[4];
    #pragma unroll
    for (int n = 0; n < 4; n++)
        pw[n] = lr * 64 + (((n * 2 + (lg >> 1)) ^ (lr & 7)) << 3) + (lg & 1) * 4;

    int nt = qB + 1;  // >= 17

    short8 kreg, vreg;
    kreg = *(const short8*)(kbase + (size_t)sr_ * DDIM + sc8 * 8);
    vreg = *(const short8*)(vtbase + (size_t)sr_ * SDIM + sc8 * 8);
    *(short8*)(Ks0 + kw) = kreg;
    *(short8*)(Vs0 + kw) = vreg;
    kreg = *(const short8*)(kbase + (size_t)(64 + sr_) * DDIM + sc8 * 8);
    vreg = *(const short8*)(vtbase + (size_t)sr_ * SDIM + 64 + sc8 * 8);
    const short* kpre = kbase + (size_t)(128 + sr_) * DDIM + sc8 * 8;
    const short* vpre = vtbase + (size_t)sr_ * SDIM + 128 + sc8 * 8;

    auto pv = [&](f32x4 (&st)[4], bool diag, int kt, short* VsC) {
        if (diag) {
            #pragma unroll
            for (int n = 0; n < 4; n++)
                #pragma unroll
                for (int j = 0; j < 4; j++) {
                    int k = kt * 64 + n * 16 + lg * 4 + j;
                    if (k > qrow) st[n][j] = -1e30f;
                }
        }
        #pragma unroll
        for (int n = 0; n < 4; n++) {
            #pragma unroll
            for (int j = 0; j < 4; j++) st[n][j] = exp2f(st[n][j]);
            lacc[n] += (st[n][0] + st[n][1]) + (st[n][2] + st[n][3]);
        }
        #pragma unroll
        for (int n = 0; n < 4; n++) {
            uint2v pk;
            pk[0] = cvtpk_bf16(st[n][0], st[n][1]);
            pk[1] = cvtpk_bf16(st[n][2], st[n][3]);
            *(uint2v*)(Ps[wave] + pw[n]) = pk;
        }
        __builtin_amdgcn_s_setprio(1);
        #pragma unroll
        for (int ks = 0; ks < 2; ks++) {
            short8 pf = *(const short8*)(Ps[wave] + po[ks]);
            #pragma unroll
            for (int n = 0; n < 4; n++) {
                short8 vf = *(const short8*)(VsC + fo[ks * 4 + n]);
                oacc[n] = __builtin_amdgcn_mfma_f32_16x16x32_bf16(pf, vf, oacc[n], 0, 0, 0);
            }
        }
        __builtin_amdgcn_s_setprio(0);
    };

    auto tile = [&](int kt, short* KsC, short* VsC, short* KsN, short* VsN) {
        __syncthreads();
        if (kt + 1 < nt) {
            *(short8*)(KsN + kw) = kreg;
            *(short8*)(VsN + kw) = vreg;
        }
        if (kt + 2 < nt) {
            kreg = *(const short8*)(kpre);
            vreg = *(const short8*)(vpre);
        }
        kpre += 64 * DDIM;
        vpre += 64;

        bool act = grp ? (kt <= qA) : true;
        if (act) {
            f32x4 st[4] = {};
            __builtin_amdgcn_s_setprio(1);
            #pragma unroll
            for (int ks = 0; ks < 2; ks++) {
                short8 kf[4];
                #pragma unroll
                for (int n = 0; n < 4; n++) kf[n] = *(const short8*)(KsC + fo[ks * 4 + n]);
                #pragma unroll
                for (int n = 0; n < 4; n++)
                    st[n] = __builtin_amdgcn_mfma_f32_16x16x32_bf16(kf[n], qf[ks], st[n], 0, 0, 0);
            }
            __builtin_amdgcn_s_setprio(0);
            pv(st, kt == qt_own, kt, VsC);
        }
    };

    for (int kt = 0; kt < nt; kt += 2) {
        tile(kt, Ks0, Vs0, Ks1, Vs1);
        if (kt + 1 < nt) tile(kt + 1, Ks1, Vs1, Ks0, Vs0);
    }

    float l = (lacc[0] + lacc[1]) + (lacc[2] + lacc[3]);
    l += __shfl_xor(l, 16);
    l += __shfl_xor(l, 32);
    int b = bh >> 4, h = bh & 15;
    float linv[4];
    #pragma unroll
    for (int j = 0; j < 4; j++)
        linv[j] = 1.f / __int_as_float(__builtin_amdgcn_ds_bpermute((lg * 4 + j) * 4, __float_as_int(l)));
    #pragma unroll
    for (int n = 0; n < 4; n++)
        #pragma unroll
        for (int j = 0; j < 4; j++) {
            int s = qt_own * 64 + wv * 16 + lg * 4 + j;
            int dd = n * 16 + lr;
            O[(((size_t)(b * SDIM + s) * HDIM) + h) * DDIM + dd] = f2bf(oacc[n][j] * linv[j]);
        }
}

extern "C" void kernel_launch(void* const* d_in, const int* in_sizes, int n_in,
                              void* d_out, int out_size, void* d_ws, size_t ws_size,
                              hipStream_t stream) {
    const float* x  = (const float*)d_in[0];
    const float* Wq = (const float*)d_in[1];
    const float* bq = (const float*)d_in[2];
    const float* Wk = (const float*)d_in[3];
    const float* bk = (const float*)d_in[4];
    const float* Wv = (const float*)d_in[5];
    const float* bv = (const float*)d_in[6];
    const float* Wo = (const float*)d_in[7];
    const float* bo = (const float*)d_in[8];
    const float* fc = (const float*)d_in[10];
    const float* fs = (const float*)d_in[11];
    float* out = (float*)d_out;
    short* ws  = (short*)d_ws;

    const size_t MM = (size_t)HID * HID;
    short* xb     = ws;
    short* wt_qkv = ws + 4 * MM;
    short* wot    = ws + 7 * MM;
    short* qt     = ws + 8 * MM;
    short* ktb    = ws + 12 * MM;
    short* vtb    = ws + 16 * MM;   // [B,H,D,S]
    short* ao     = ws + 20 * MM;

    cvt_bf16<<<dim3((MDIM * HID) / (256 * 8)), 256, 0, stream>>>(x, xb, MDIM * HID);
    transpose4<<<dim3(16, 16, 4), 256, 0, stream>>>(Wq, Wk, Wv, Wo,
                                                    wt_qkv, wt_qkv + MM, wt_qkv + 2 * MM, wot);
    gemm_bf16<<<dim3(MDIM / 128, HID / 128, 3), 256, 0, stream>>>(
        xb, wt_qkv, bq, bk, bv, fc, fs, qt, nullptr, 0);
    attn_fwd<<<dim3(16, BDIM * HDIM), 512, 0, stream>>>(qt, ktb, vtb, ao);
    gemm_bf16<<<dim3(MDIM / 128, HID / 128, 1), 256, 0, stream>>>(
        ao, wot, bo, bo, bo, fc, fs, nullptr, out, 3);
}

// Round 20
// 103.182 us; speedup vs baseline: 1.1925x; 1.0514x over previous
//
#include <hip/hip_runtime.h>
#include <hip/hip_bf16.h>

#define BDIM 2
#define SDIM 2048
#define HDIM 16
#define DDIM 64
#define HID  1024
#define MDIM (BDIM * SDIM)  // 4096

typedef __attribute__((ext_vector_type(8))) short short8;
typedef __attribute__((ext_vector_type(4))) short short4v;
typedef __attribute__((ext_vector_type(4))) float f32x4;
typedef __attribute__((ext_vector_type(2))) unsigned int uint2v;

__device__ __forceinline__ float bf2f(short u) {
    union { unsigned int i; float f; } x;
    x.i = ((unsigned int)(unsigned short)u) << 16;
    return x.f;
}
__device__ __forceinline__ short f2bf(float f) {
    union { float f; unsigned int i; } x; x.f = f;
    unsigned int r = x.i + 0x7fffu + ((x.i >> 16) & 1u);
    return (short)(r >> 16);
}
__device__ __forceinline__ unsigned int cvtpk_bf16(float lo, float hi) {
    unsigned int r;
    asm("v_cvt_pk_bf16_f32 %0, %1, %2" : "=v"(r) : "v"(lo), "v"(hi));
    return r;
}
// swizzled short-index into a [rows][64 shorts] tile; c8 = 16B chunk (0..7)
__device__ __forceinline__ int swz(int row, int c8) {
    return row * 64 + ((c8 ^ (row & 7)) << 3);
}

// ---------------- convert f32 -> bf16 (8 elems/thread) ----------------
__global__ __launch_bounds__(256) void cvt_bf16(const float* __restrict__ in,
                                               short* __restrict__ out, int n) {
    int i = (blockIdx.x * 256 + threadIdx.x) * 8;
    if (i >= n) return;
    float4 a = *(const float4*)(in + i);
    float4 b = *(const float4*)(in + i + 4);
    short8 v;
    v[0] = f2bf(a.x); v[1] = f2bf(a.y); v[2] = f2bf(a.z); v[3] = f2bf(a.w);
    v[4] = f2bf(b.x); v[5] = f2bf(b.y); v[6] = f2bf(b.z); v[7] = f2bf(b.w);
    *(short8*)(out + i) = v;
}

// ------------- transpose 4 f32 weights [K][N] -> bf16 [N][K] -------------
__global__ __launch_bounds__(256) void transpose4(
    const float* __restrict__ w0, const float* __restrict__ w1,
    const float* __restrict__ w2, const float* __restrict__ w3,
    short* __restrict__ o0, short* __restrict__ o1,
    short* __restrict__ o2, short* __restrict__ o3)
{
    const float* src; short* dst;
    int z = blockIdx.z;
    if (z == 0)      { src = w0; dst = o0; }
    else if (z == 1) { src = w1; dst = o1; }
    else if (z == 2) { src = w2; dst = o2; }
    else             { src = w3; dst = o3; }
    __shared__ float t[64][65];
    int r0 = blockIdx.y * 64, c0 = blockIdx.x * 64;
    int rd_r = threadIdx.x >> 4, rd_c = (threadIdx.x & 15) * 4;
    #pragma unroll
    for (int it = 0; it < 4; it++) {
        int rr = rd_r + it * 16;
        float4 v = *(const float4*)(src + (size_t)(r0 + rr) * HID + c0 + rd_c);
        t[rr][rd_c + 0] = v.x; t[rr][rd_c + 1] = v.y;
        t[rr][rd_c + 2] = v.z; t[rr][rd_c + 3] = v.w;
    }
    __syncthreads();
    int or_ = threadIdx.x >> 3, oc8 = (threadIdx.x & 7) * 8;
    #pragma unroll
    for (int half = 0; half < 2; half++) {
        int dr = or_ + half * 32;
        short8 v;
        #pragma unroll
        for (int i = 0; i < 8; i++) v[i] = f2bf(t[oc8 + i][dr]);
        *(short8*)(dst + (size_t)(c0 + dr) * HID + r0 + oc8) = v;
    }
}

// ------- GEMM, 8-wave 128x128 tile, 2-phase dbuf reg-staging -------
// out = X[M,1024](bf16) @ Wt(bf16,[N][K]) + bias(f32)
// mode 0/1: q/k + RoPE -> [B,H,S,D]; mode 2: v -> V^T [B,H,D,S]; mode 3: f32 [M,N]
// 512 threads: each stages exactly one A + one B short8/K-step (full 128x32
// tile). Wave (wr,wc) in 2x4 grid owns 64x32 output (acc[4][2], 8 MFMA/step).
// XOR swizzle chunk^=(row>>1)&3 write+read: conflict-free (R19: counter = 0).
// 24 waves/CU (vs 12 at 4-wave) -> 2x latency hiding on the barrier drain.
__global__ __launch_bounds__(512) void gemm_bf16(
    const short* __restrict__ X,
    const short* __restrict__ Wt0,
    const float* __restrict__ b0, const float* __restrict__ b1, const float* __restrict__ b2,
    const float* __restrict__ cosb, const float* __restrict__ sinb,
    short* __restrict__ out0, float* __restrict__ outf,
    int modeBase)
{
    __shared__ __align__(16) short Asm[2][128 * 32];   // 16 KB
    __shared__ __align__(16) short Bsm[2][128 * 32];   // 16 KB
    int z = blockIdx.z;
    int mode = modeBase + z;
    const short* Wt = Wt0 + (size_t)z * HID * HID;
    const float* bias = (z == 0) ? b0 : (z == 1) ? b1 : b2;
    short* outp = out0 + (size_t)z * MDIM * HID;

    int tid = threadIdx.x;
    int lane = tid & 63, wave = tid >> 6;   // wave 0..7
    int wr = wave >> 2, wc = wave & 3;      // 2 x 4 wave grid
    int m0 = blockIdx.x * 128, n0 = blockIdx.y * 128;
    int sr = tid >> 2, sc = (tid & 3) * 8;  // sr 0..127: full tile coverage
    int lr = lane & 15, lg = lane >> 4;

    const short* ax = X  + (size_t)(m0 + sr) * HID + sc;
    const short* bx = Wt + (size_t)(n0 + sr) * HID + sc;
    // swizzled write offset: phys chunk = (tid&3) ^ ((sr>>1)&3)
    int csw = ((tid & 3) ^ ((sr >> 1) & 3)) * 8;
    int wA  = sr * 32 + csw;
    // swizzled read offset: logical chunk lg at row ..+lr -> phys lg^((lr>>1)&3)
    int rdsw = (lg ^ ((lr >> 1) & 3)) * 8;

    f32x4 acc[4][2] = {};
    constexpr int NK = HID / 32;  // 32 K-steps

    short8 a0, b0v;
    // prologue: k=0 -> buf0, k=1 -> regs
    a0  = *(const short8*)(ax);
    b0v = *(const short8*)(bx);
    *(short8*)(Asm[0] + wA) = a0;
    *(short8*)(Bsm[0] + wA) = b0v;
    a0  = *(const short8*)(ax + 32);
    b0v = *(const short8*)(bx + 32);

    int cur = 0;
    for (int ki = 0; ki < NK; ki++) {
        __syncthreads();     // buf[cur] ready; buf[cur^1] free
        if (ki + 1 < NK) {   // stage next tile into other buffer
            *(short8*)(Asm[cur ^ 1] + wA) = a0;
            *(short8*)(Bsm[cur ^ 1] + wA) = b0v;
        }
        if (ki + 2 < NK) {   // T14: issue loads 2 steps ahead
            int k0 = (ki + 2) * 32;
            a0  = *(const short8*)(ax + k0);
            b0v = *(const short8*)(bx + k0);
        }
        short8 af[4], bfr[2];
        #pragma unroll
        for (int m = 0; m < 4; m++)
            af[m] = *(const short8*)(Asm[cur] + (wr * 64 + m * 16 + lr) * 32 + rdsw);
        #pragma unroll
        for (int n = 0; n < 2; n++)
            bfr[n] = *(const short8*)(Bsm[cur] + (wc * 32 + n * 16 + lr) * 32 + rdsw);
        __builtin_amdgcn_s_setprio(1);
        #pragma unroll
        for (int m = 0; m < 4; m++)
            #pragma unroll
            for (int n = 0; n < 2; n++)
                acc[m][n] = __builtin_amdgcn_mfma_f32_16x16x32_bf16(af[m], bfr[n], acc[m][n], 0, 0, 0);
        __builtin_amdgcn_s_setprio(0);
        cur ^= 1;
    }

    #pragma unroll
    for (int m = 0; m < 4; m++) {
        #pragma unroll
        for (int n = 0; n < 2; n++) {
            int gr0 = m0 + wr * 64 + m * 16 + lg * 4;
            int gc  = n0 + wc * 32 + n * 16 + lr;
            if (mode == 3) {
                #pragma unroll
                for (int j = 0; j < 4; j++)
                    outf[(size_t)(gr0 + j) * HID + gc] = acc[m][n][j] + bias[gc];
            } else if (mode == 2) {
                int bb = gr0 >> 11, s0 = gr0 & (SDIM - 1);
                int h = gc >> 6, dd = gc & 63;
                short4v pk;
                #pragma unroll
                for (int j = 0; j < 4; j++) pk[j] = f2bf(acc[m][n][j] + bias[gc]);
                *(short4v*)(outp + ((size_t)((bb * HDIM + h) * DDIM + dd)) * SDIM + s0) = pk;
            } else {
                #pragma unroll
                for (int j = 0; j < 4; j++) {
                    int gr = gr0 + j;
                    int bb = gr >> 11, s = gr & (SDIM - 1);
                    int h = gc >> 6, dd = gc & 63;
                    float v = acc[m][n][j] + bias[gc];
                    float p  = __shfl_xor(v, 1);
                    float cc = cosb[s * 32 + (dd >> 1)];
                    float ss = sinb[s * 32 + (dd >> 1)];
                    v = (dd & 1) ? (p * ss + v * cc) : (v * cc - p * ss);
                    outp[((size_t)((bb * HDIM + h) * SDIM + s)) * DDIM + dd] = f2bf(v);
                }
            }
        }
    }
}

// ------- causal flash attention: 8-wave blocks, maxless softmax -------
// (unchanged from R19 — best measured attn)
__global__ __launch_bounds__(512) void attn_fwd(
    const short* __restrict__ Q,
    const short* __restrict__ K,
    const short* __restrict__ Vt,
    short* __restrict__ O)
{
    __shared__ __align__(16) short Ks0[64 * 64], Ks1[64 * 64];
    __shared__ __align__(16) short Vs0[64 * 64], Vs1[64 * 64];
    __shared__ __align__(16) short Ps[8][16 * 64];
    int bx = blockIdx.x;                  // 0..15
    int qA = bx, qB = 31 - bx;            // qA < qB
    int bh = blockIdx.y;
    int tid = threadIdx.x;
    int lane = tid & 63, wave = tid >> 6;  // wave 0..7
    int wv = wave & 3, grp = wave >> 2;    // grp 0 -> qB, grp 1 -> qA
    int lr = lane & 15, lg = lane >> 4;
    const short* qbase  = Q  + ((size_t)bh * SDIM) * DDIM;
    const short* kbase  = K  + ((size_t)bh * SDIM) * DDIM;
    const short* vtbase = Vt + ((size_t)bh * DDIM) * SDIM;

    const float SCALE = 0.125f * 1.44269504088896340736f;  // 1/sqrt(64) * log2(e)

    int qt_own = grp ? qA : qB;
    int qrow = qt_own * 64 + wv * 16 + lr;

    short8 qf[2];
    #pragma unroll
    for (int ks = 0; ks < 2; ks++) {
        short8 a = *(const short8*)(qbase + (size_t)qrow * DDIM + ks * 32 + lg * 8);
        short8 ra;
        #pragma unroll
        for (int i = 0; i < 8; i++) ra[i] = f2bf(bf2f(a[i]) * SCALE);
        qf[ks] = ra;
    }

    f32x4 lacc = {0.f, 0.f, 0.f, 0.f};
    f32x4 oacc[4] = {};

    int sr_ = tid >> 3, sc8 = tid & 7;
    int kw = swz(sr_, sc8);
    int fo[8];
    #pragma unroll
    for (int ks = 0; ks < 2; ks++)
        #pragma unroll
        for (int n = 0; n < 4; n++) fo[ks * 4 + n] = swz(n * 16 + lr, ks * 4 + lg);
    int po[2] = { swz(lr, lg), swz(lr, 4 + lg) };
    int pw[4];
    #pragma unroll
    for (int n = 0; n < 4; n++)
        pw[n] = lr * 64 + (((n * 2 + (lg >> 1)) ^ (lr & 7)) << 3) + (lg & 1) * 4;

    int nt = qB + 1;  // >= 17

    short8 kreg, vreg;
    kreg = *(const short8*)(kbase + (size_t)sr_ * DDIM + sc8 * 8);
    vreg = *(const short8*)(vtbase + (size_t)sr_ * SDIM + sc8 * 8);
    *(short8*)(Ks0 + kw) = kreg;
    *(short8*)(Vs0 + kw) = vreg;
    kreg = *(const short8*)(kbase + (size_t)(64 + sr_) * DDIM + sc8 * 8);
    vreg = *(const short8*)(vtbase + (size_t)sr_ * SDIM + 64 + sc8 * 8);
    const short* kpre = kbase + (size_t)(128 + sr_) * DDIM + sc8 * 8;
    const short* vpre = vtbase + (size_t)sr_ * SDIM + 128 + sc8 * 8;

    auto pv = [&](f32x4 (&st)[4], bool diag, int kt, short* VsC) {
        if (diag) {
            #pragma unroll
            for (int n = 0; n < 4; n++)
                #pragma unroll
                for (int j = 0; j < 4; j++) {
                    int k = kt * 64 + n * 16 + lg * 4 + j;
                    if (k > qrow) st[n][j] = -1e30f;
                }
        }
        #pragma unroll
        for (int n = 0; n < 4; n++) {
            #pragma unroll
            for (int j = 0; j < 4; j++) st[n][j] = exp2f(st[n][j]);
            lacc[n] += (st[n][0] + st[n][1]) + (st[n][2] + st[n][3]);
        }
        #pragma unroll
        for (int n = 0; n < 4; n++) {
            uint2v pk;
            pk[0] = cvtpk_bf16(st[n][0], st[n][1]);
            pk[1] = cvtpk_bf16(st[n][2], st[n][3]);
            *(uint2v*)(Ps[wave] + pw[n]) = pk;
        }
        __builtin_amdgcn_s_setprio(1);
        #pragma unroll
        for (int ks = 0; ks < 2; ks++) {
            short8 pf = *(const short8*)(Ps[wave] + po[ks]);
            #pragma unroll
            for (int n = 0; n < 4; n++) {
                short8 vf = *(const short8*)(VsC + fo[ks * 4 + n]);
                oacc[n] = __builtin_amdgcn_mfma_f32_16x16x32_bf16(pf, vf, oacc[n], 0, 0, 0);
            }
        }
        __builtin_amdgcn_s_setprio(0);
    };

    auto tile = [&](int kt, short* KsC, short* VsC, short* KsN, short* VsN) {
        __syncthreads();
        if (kt + 1 < nt) {
            *(short8*)(KsN + kw) = kreg;
            *(short8*)(VsN + kw) = vreg;
        }
        if (kt + 2 < nt) {
            kreg = *(const short8*)(kpre);
            vreg = *(const short8*)(vpre);
        }
        kpre += 64 * DDIM;
        vpre += 64;

        bool act = grp ? (kt <= qA) : true;
        if (act) {
            f32x4 st[4] = {};
            __builtin_amdgcn_s_setprio(1);
            #pragma unroll
            for (int ks = 0; ks < 2; ks++) {
                short8 kf[4];
                #pragma unroll
                for (int n = 0; n < 4; n++) kf[n] = *(const short8*)(KsC + fo[ks * 4 + n]);
                #pragma unroll
                for (int n = 0; n < 4; n++)
                    st[n] = __builtin_amdgcn_mfma_f32_16x16x32_bf16(kf[n], qf[ks], st[n], 0, 0, 0);
            }
            __builtin_amdgcn_s_setprio(0);
            pv(st, kt == qt_own, kt, VsC);
        }
    };

    for (int kt = 0; kt < nt; kt += 2) {
        tile(kt, Ks0, Vs0, Ks1, Vs1);
        if (kt + 1 < nt) tile(kt + 1, Ks1, Vs1, Ks0, Vs0);
    }

    float l = (lacc[0] + lacc[1]) + (lacc[2] + lacc[3]);
    l += __shfl_xor(l, 16);
    l += __shfl_xor(l, 32);
    int b = bh >> 4, h = bh & 15;
    float linv[4];
    #pragma unroll
    for (int j = 0; j < 4; j++)
        linv[j] = 1.f / __int_as_float(__builtin_amdgcn_ds_bpermute((lg * 4 + j) * 4, __float_as_int(l)));
    #pragma unroll
    for (int n = 0; n < 4; n++)
        #pragma unroll
        for (int j = 0; j < 4; j++) {
            int s = qt_own * 64 + wv * 16 + lg * 4 + j;
            int dd = n * 16 + lr;
            O[(((size_t)(b * SDIM + s) * HDIM) + h) * DDIM + dd] = f2bf(oacc[n][j] * linv[j]);
        }
}

extern "C" void kernel_launch(void* const* d_in, const int* in_sizes, int n_in,
                              void* d_out, int out_size, void* d_ws, size_t ws_size,
                              hipStream_t stream) {
    const float* x  = (const float*)d_in[0];
    const float* Wq = (const float*)d_in[1];
    const float* bq = (const float*)d_in[2];
    const float* Wk = (const float*)d_in[3];
    const float* bk = (const float*)d_in[4];
    const float* Wv = (const float*)d_in[5];
    const float* bv = (const float*)d_in[6];
    const float* Wo = (const float*)d_in[7];
    const float* bo = (const float*)d_in[8];
    const float* fc = (const float*)d_in[10];
    const float* fs = (const float*)d_in[11];
    float* out = (float*)d_out;
    short* ws  = (short*)d_ws;

    const size_t MM = (size_t)HID * HID;
    short* xb     = ws;
    short* wt_qkv = ws + 4 * MM;
    short* wot    = ws + 7 * MM;
    short* qt     = ws + 8 * MM;
    short* ktb    = ws + 12 * MM;
    short* vtb    = ws + 16 * MM;   // [B,H,D,S]
    short* ao     = ws + 20 * MM;

    cvt_bf16<<<dim3((MDIM * HID) / (256 * 8)), 256, 0, stream>>>(x, xb, MDIM * HID);
    transpose4<<<dim3(16, 16, 4), 256, 0, stream>>>(Wq, Wk, Wv, Wo,
                                                    wt_qkv, wt_qkv + MM, wt_qkv + 2 * MM, wot);
    gemm_bf16<<<dim3(MDIM / 128, HID / 128, 3), 512, 0, stream>>>(
        xb, wt_qkv, bq, bk, bv, fc, fs, qt, nullptr, 0);
    attn_fwd<<<dim3(16, BDIM * HDIM), 512, 0, stream>>>(qt, ktb, vtb, ao);
    gemm_bf16<<<dim3(MDIM / 128, HID / 128, 1), 512, 0, stream>>>(
        ao, wot, bo, bo, bo, fc, fs, nullptr, out, 3);
}

// Round 21
// 102.944 us; speedup vs baseline: 1.1952x; 1.0023x over previous
//
#include <hip/hip_runtime.h>
#include <hip/hip_bf16.h>

#define BDIM 2
#define SDIM 2048
#define HDIM 16
#define DDIM 64
#define HID  1024
#define MDIM (BDIM * SDIM)  // 4096

typedef __attribute__((ext_vector_type(8))) short short8;
typedef __attribute__((ext_vector_type(4))) short short4v;
typedef __attribute__((ext_vector_type(4))) float f32x4;
typedef __attribute__((ext_vector_type(2))) unsigned int uint2v;

__device__ __forceinline__ float bf2f(short u) {
    union { unsigned int i; float f; } x;
    x.i = ((unsigned int)(unsigned short)u) << 16;
    return x.f;
}
__device__ __forceinline__ short f2bf(float f) {
    union { float f; unsigned int i; } x; x.f = f;
    unsigned int r = x.i + 0x7fffu + ((x.i >> 16) & 1u);
    return (short)(r >> 16);
}
__device__ __forceinline__ unsigned int cvtpk_bf16(float lo, float hi) {
    unsigned int r;
    asm("v_cvt_pk_bf16_f32 %0, %1, %2" : "=v"(r) : "v"(lo), "v"(hi));
    return r;
}
// swizzled short-index into a [rows][64 shorts] tile; c8 = 16B chunk (0..7)
__device__ __forceinline__ int swz(int row, int c8) {
    return row * 64 + ((c8 ^ (row & 7)) << 3);
}

// ------- merged prep: cvt x->bf16 (blocks 0..2047) + weight transpose -------
// (blocks 2048..3071: 4 matrices x 256 tiles of 64x64, f32 [K][N] -> bf16 [N][K])
__global__ __launch_bounds__(256) void prep(
    const float* __restrict__ x, short* __restrict__ xb,
    const float* __restrict__ w0, const float* __restrict__ w1,
    const float* __restrict__ w2, const float* __restrict__ w3,
    short* __restrict__ o0, short* __restrict__ o1,
    short* __restrict__ o2, short* __restrict__ o3)
{
    int bid = blockIdx.x;
    if (bid < 2048) {
        int i = (bid * 256 + threadIdx.x) * 8;
        float4 a = *(const float4*)(x + i);
        float4 b = *(const float4*)(x + i + 4);
        short8 v;
        v[0] = f2bf(a.x); v[1] = f2bf(a.y); v[2] = f2bf(a.z); v[3] = f2bf(a.w);
        v[4] = f2bf(b.x); v[5] = f2bf(b.y); v[6] = f2bf(b.z); v[7] = f2bf(b.w);
        *(short8*)(xb + i) = v;
        return;
    }
    __shared__ float t[64][65];
    int b = bid - 2048;
    int z = b >> 8, rem = b & 255;
    const float* src; short* dst;
    if (z == 0)      { src = w0; dst = o0; }
    else if (z == 1) { src = w1; dst = o1; }
    else if (z == 2) { src = w2; dst = o2; }
    else             { src = w3; dst = o3; }
    int r0 = (rem >> 4) * 64, c0 = (rem & 15) * 64;
    int rd_r = threadIdx.x >> 4, rd_c = (threadIdx.x & 15) * 4;
    #pragma unroll
    for (int it = 0; it < 4; it++) {
        int rr = rd_r + it * 16;
        float4 v = *(const float4*)(src + (size_t)(r0 + rr) * HID + c0 + rd_c);
        t[rr][rd_c + 0] = v.x; t[rr][rd_c + 1] = v.y;
        t[rr][rd_c + 2] = v.z; t[rr][rd_c + 3] = v.w;
    }
    __syncthreads();
    int or_ = threadIdx.x >> 3, oc8 = (threadIdx.x & 7) * 8;
    #pragma unroll
    for (int half = 0; half < 2; half++) {
        int dr = or_ + half * 32;
        short8 v;
        #pragma unroll
        for (int i = 0; i < 8; i++) v[i] = f2bf(t[oc8 + i][dr]);
        *(short8*)(dst + (size_t)(c0 + dr) * HID + r0 + oc8) = v;
    }
}

// ------- GEMM, 8-wave 128x128 tile, 2-phase dbuf reg-staging (R20 best) -------
__global__ __launch_bounds__(512) void gemm_bf16(
    const short* __restrict__ X,
    const short* __restrict__ Wt0,
    const float* __restrict__ b0, const float* __restrict__ b1, const float* __restrict__ b2,
    const float* __restrict__ cosb, const float* __restrict__ sinb,
    short* __restrict__ out0, float* __restrict__ outf,
    int modeBase)
{
    __shared__ __align__(16) short Asm[2][128 * 32];   // 16 KB
    __shared__ __align__(16) short Bsm[2][128 * 32];   // 16 KB
    int z = blockIdx.z;
    int mode = modeBase + z;
    const short* Wt = Wt0 + (size_t)z * HID * HID;
    const float* bias = (z == 0) ? b0 : (z == 1) ? b1 : b2;
    short* outp = out0 + (size_t)z * MDIM * HID;

    int tid = threadIdx.x;
    int lane = tid & 63, wave = tid >> 6;   // wave 0..7
    int wr = wave >> 2, wc = wave & 3;      // 2 x 4 wave grid
    int m0 = blockIdx.x * 128, n0 = blockIdx.y * 128;
    int sr = tid >> 2, sc = (tid & 3) * 8;  // sr 0..127: full tile coverage
    int lr = lane & 15, lg = lane >> 4;

    const short* ax = X  + (size_t)(m0 + sr) * HID + sc;
    const short* bx = Wt + (size_t)(n0 + sr) * HID + sc;
    int csw = ((tid & 3) ^ ((sr >> 1) & 3)) * 8;
    int wA  = sr * 32 + csw;
    int rdsw = (lg ^ ((lr >> 1) & 3)) * 8;

    f32x4 acc[4][2] = {};
    constexpr int NK = HID / 32;  // 32 K-steps

    short8 a0, b0v;
    a0  = *(const short8*)(ax);
    b0v = *(const short8*)(bx);
    *(short8*)(Asm[0] + wA) = a0;
    *(short8*)(Bsm[0] + wA) = b0v;
    a0  = *(const short8*)(ax + 32);
    b0v = *(const short8*)(bx + 32);

    int cur = 0;
    for (int ki = 0; ki < NK; ki++) {
        __syncthreads();
        if (ki + 1 < NK) {
            *(short8*)(Asm[cur ^ 1] + wA) = a0;
            *(short8*)(Bsm[cur ^ 1] + wA) = b0v;
        }
        if (ki + 2 < NK) {
            int k0 = (ki + 2) * 32;
            a0  = *(const short8*)(ax + k0);
            b0v = *(const short8*)(bx + k0);
        }
        short8 af[4], bfr[2];
        #pragma unroll
        for (int m = 0; m < 4; m++)
            af[m] = *(const short8*)(Asm[cur] + (wr * 64 + m * 16 + lr) * 32 + rdsw);
        #pragma unroll
        for (int n = 0; n < 2; n++)
            bfr[n] = *(const short8*)(Bsm[cur] + (wc * 32 + n * 16 + lr) * 32 + rdsw);
        __builtin_amdgcn_s_setprio(1);
        #pragma unroll
        for (int m = 0; m < 4; m++)
            #pragma unroll
            for (int n = 0; n < 2; n++)
                acc[m][n] = __builtin_amdgcn_mfma_f32_16x16x32_bf16(af[m], bfr[n], acc[m][n], 0, 0, 0);
        __builtin_amdgcn_s_setprio(0);
        cur ^= 1;
    }

    #pragma unroll
    for (int m = 0; m < 4; m++) {
        #pragma unroll
        for (int n = 0; n < 2; n++) {
            int gr0 = m0 + wr * 64 + m * 16 + lg * 4;
            int gc  = n0 + wc * 32 + n * 16 + lr;
            if (mode == 3) {
                #pragma unroll
                for (int j = 0; j < 4; j++)
                    outf[(size_t)(gr0 + j) * HID + gc] = acc[m][n][j] + bias[gc];
            } else if (mode == 2) {
                int bb = gr0 >> 11, s0 = gr0 & (SDIM - 1);
                int h = gc >> 6, dd = gc & 63;
                short4v pk;
                #pragma unroll
                for (int j = 0; j < 4; j++) pk[j] = f2bf(acc[m][n][j] + bias[gc]);
                *(short4v*)(outp + ((size_t)((bb * HDIM + h) * DDIM + dd)) * SDIM + s0) = pk;
            } else {
                #pragma unroll
                for (int j = 0; j < 4; j++) {
                    int gr = gr0 + j;
                    int bb = gr >> 11, s = gr & (SDIM - 1);
                    int h = gc >> 6, dd = gc & 63;
                    float v = acc[m][n][j] + bias[gc];
                    float p  = __shfl_xor(v, 1);
                    float cc = cosb[s * 32 + (dd >> 1)];
                    float ss = sinb[s * 32 + (dd >> 1)];
                    v = (dd & 1) ? (p * ss + v * cc) : (v * cc - p * ss);
                    outp[((size_t)((bb * HDIM + h) * SDIM + s)) * DDIM + dd] = f2bf(v);
                }
            }
        }
    }
}

// ------- causal flash attention: 8-wave, maxless softmax, paired KV tiles ----
// Stage TWO 64-row KV tiles per barrier (pair = 128 kv rows): barriers per
// block-pass 33 -> 17; inner math identical per 64-kv pass. LDS 80KB -> still
// 2 blocks/CU (grid-capped at 2 anyway).
__global__ __launch_bounds__(512) void attn_fwd(
    const short* __restrict__ Q,
    const short* __restrict__ K,
    const short* __restrict__ Vt,
    short* __restrict__ O)
{
    __shared__ __align__(16) short Ks[2][2][64 * 64];   // [dbuf][half]
    __shared__ __align__(16) short Vs[2][2][64 * 64];
    __shared__ __align__(16) short Ps[8][16 * 64];
    int bx = blockIdx.x;                  // 0..15
    int qA = bx, qB = 31 - bx;            // qA < qB
    int bh = blockIdx.y;
    int tid = threadIdx.x;
    int lane = tid & 63, wave = tid >> 6;  // wave 0..7
    int wv = wave & 3, grp = wave >> 2;    // grp 0 -> qB, grp 1 -> qA
    int lr = lane & 15, lg = lane >> 4;
    const short* qbase  = Q  + ((size_t)bh * SDIM) * DDIM;
    const short* kbase  = K  + ((size_t)bh * SDIM) * DDIM;
    const short* vtbase = Vt + ((size_t)bh * DDIM) * SDIM;

    const float SCALE = 0.125f * 1.44269504088896340736f;  // 1/sqrt(64) * log2(e)

    int qt_own = grp ? qA : qB;
    int qrow = qt_own * 64 + wv * 16 + lr;

    short8 qf[2];
    #pragma unroll
    for (int ks = 0; ks < 2; ks++) {
        short8 a = *(const short8*)(qbase + (size_t)qrow * DDIM + ks * 32 + lg * 8);
        short8 ra;
        #pragma unroll
        for (int i = 0; i < 8; i++) ra[i] = f2bf(bf2f(a[i]) * SCALE);
        qf[ks] = ra;
    }

    f32x4 lacc = {0.f, 0.f, 0.f, 0.f};
    f32x4 oacc[4] = {};

    int sr_ = tid >> 3, sc8 = tid & 7;
    int kw = swz(sr_, sc8);
    int fo[8];
    #pragma unroll
    for (int ks = 0; ks < 2; ks++)
        #pragma unroll
        for (int n = 0; n < 4; n++) fo[ks * 4 + n] = swz(n * 16 + lr, ks * 4 + lg);
    int po[2] = { swz(lr, lg), swz(lr, 4 + lg) };
    int pw[4];
    #pragma unroll
    for (int n = 0; n < 4; n++)
        pw[n] = lr * 64 + (((n * 2 + (lg >> 1)) ^ (lr & 7)) << 3) + (lg & 1) * 4;

    int nt64 = qB + 1;                 // 64-row kv tiles needed
    int npairs = qB / 2 + 1;           // 128-row pairs staged

    // prologue: pair 0 -> buf0; pair 1 -> regs
    short8 kA, kB, vA, vB;
    kA = *(const short8*)(kbase + (size_t)sr_ * DDIM + sc8 * 8);
    kB = *(const short8*)(kbase + (size_t)(64 + sr_) * DDIM + sc8 * 8);
    vA = *(const short8*)(vtbase + (size_t)sr_ * SDIM + sc8 * 8);
    vB = *(const short8*)(vtbase + (size_t)sr_ * SDIM + 64 + sc8 * 8);
    *(short8*)(Ks[0][0] + kw) = kA;
    *(short8*)(Ks[0][1] + kw) = kB;
    *(short8*)(Vs[0][0] + kw) = vA;
    *(short8*)(Vs[0][1] + kw) = vB;
    if (npairs > 1) {
        kA = *(const short8*)(kbase + (size_t)(128 + sr_) * DDIM + sc8 * 8);
        kB = *(const short8*)(kbase + (size_t)(192 + sr_) * DDIM + sc8 * 8);
        vA = *(const short8*)(vtbase + (size_t)sr_ * SDIM + 128 + sc8 * 8);
        vB = *(const short8*)(vtbase + (size_t)sr_ * SDIM + 192 + sc8 * 8);
    }
    const short* kpre = kbase + (size_t)(256 + sr_) * DDIM + sc8 * 8;
    const short* vpre = vtbase + (size_t)sr_ * SDIM + 256 + sc8 * 8;

    auto pv = [&](f32x4 (&st)[4], bool diag, int k64, short* VsC) {
        if (diag) {
            #pragma unroll
            for (int n = 0; n < 4; n++)
                #pragma unroll
                for (int j = 0; j < 4; j++) {
                    int k = k64 * 64 + n * 16 + lg * 4 + j;
                    if (k > qrow) st[n][j] = -1e30f;
                }
        }
        #pragma unroll
        for (int n = 0; n < 4; n++) {
            #pragma unroll
            for (int j = 0; j < 4; j++) st[n][j] = exp2f(st[n][j]);
            lacc[n] += (st[n][0] + st[n][1]) + (st[n][2] + st[n][3]);
        }
        #pragma unroll
        for (int n = 0; n < 4; n++) {
            uint2v pk;
            pk[0] = cvtpk_bf16(st[n][0], st[n][1]);
            pk[1] = cvtpk_bf16(st[n][2], st[n][3]);
            *(uint2v*)(Ps[wave] + pw[n]) = pk;
        }
        __builtin_amdgcn_s_setprio(1);
        #pragma unroll
        for (int ks = 0; ks < 2; ks++) {
            short8 pf = *(const short8*)(Ps[wave] + po[ks]);
            #pragma unroll
            for (int n = 0; n < 4; n++) {
                short8 vf = *(const short8*)(VsC + fo[ks * 4 + n]);
                oacc[n] = __builtin_amdgcn_mfma_f32_16x16x32_bf16(pf, vf, oacc[n], 0, 0, 0);
            }
        }
        __builtin_amdgcn_s_setprio(0);
    };

    int cur = 0;
    for (int kt = 0; kt < npairs; kt++) {
        __syncthreads();                   // buf[cur] ready; buf[cur^1] free
        if (kt + 1 < npairs) {             // write prefetched pair
            *(short8*)(Ks[cur ^ 1][0] + kw) = kA;
            *(short8*)(Ks[cur ^ 1][1] + kw) = kB;
            *(short8*)(Vs[cur ^ 1][0] + kw) = vA;
            *(short8*)(Vs[cur ^ 1][1] + kw) = vB;
        }
        if (kt + 2 < npairs) {             // T14: prefetch pair kt+2
            kA = *(const short8*)(kpre);
            kB = *(const short8*)(kpre + (size_t)64 * DDIM);
            vA = *(const short8*)(vpre);
            vB = *(const short8*)(vpre + 64);
        }
        kpre += (size_t)128 * DDIM;
        vpre += 128;

        #pragma unroll
        for (int h = 0; h < 2; h++) {
            int k64 = kt * 2 + h;
            if (k64 >= nt64) continue;     // odd-count tail (block-uniform)
            bool act = grp ? (k64 <= qA) : true;
            if (act) {
                f32x4 st[4] = {};
                __builtin_amdgcn_s_setprio(1);
                #pragma unroll
                for (int ks = 0; ks < 2; ks++) {
                    short8 kf[4];
                    #pragma unroll
                    for (int n = 0; n < 4; n++)
                        kf[n] = *(const short8*)(Ks[cur][h] + fo[ks * 4 + n]);
                    #pragma unroll
                    for (int n = 0; n < 4; n++)
                        st[n] = __builtin_amdgcn_mfma_f32_16x16x32_bf16(kf[n], qf[ks], st[n], 0, 0, 0);
                }
                __builtin_amdgcn_s_setprio(0);
                pv(st, k64 == qt_own, k64, Vs[cur][h]);
            }
        }
        cur ^= 1;
    }

    float l = (lacc[0] + lacc[1]) + (lacc[2] + lacc[3]);
    l += __shfl_xor(l, 16);
    l += __shfl_xor(l, 32);
    int b = bh >> 4, h = bh & 15;
    float linv[4];
    #pragma unroll
    for (int j = 0; j < 4; j++)
        linv[j] = 1.f / __int_as_float(__builtin_amdgcn_ds_bpermute((lg * 4 + j) * 4, __float_as_int(l)));
    #pragma unroll
    for (int n = 0; n < 4; n++)
        #pragma unroll
        for (int j = 0; j < 4; j++) {
            int s = qt_own * 64 + wv * 16 + lg * 4 + j;
            int dd = n * 16 + lr;
            O[(((size_t)(b * SDIM + s) * HDIM) + h) * DDIM + dd] = f2bf(oacc[n][j] * linv[j]);
        }
}

extern "C" void kernel_launch(void* const* d_in, const int* in_sizes, int n_in,
                              void* d_out, int out_size, void* d_ws, size_t ws_size,
                              hipStream_t stream) {
    const float* x  = (const float*)d_in[0];
    const float* Wq = (const float*)d_in[1];
    const float* bq = (const float*)d_in[2];
    const float* Wk = (const float*)d_in[3];
    const float* bk = (const float*)d_in[4];
    const float* Wv = (const float*)d_in[5];
    const float* bv = (const float*)d_in[6];
    const float* Wo = (const float*)d_in[7];
    const float* bo = (const float*)d_in[8];
    const float* fc = (const float*)d_in[10];
    const float* fs = (const float*)d_in[11];
    float* out = (float*)d_out;
    short* ws  = (short*)d_ws;

    const size_t MM = (size_t)HID * HID;
    short* xb     = ws;
    short* wt_qkv = ws + 4 * MM;
    short* wot    = ws + 7 * MM;
    short* qt     = ws + 8 * MM;
    short* ktb    = ws + 12 * MM;
    short* vtb    = ws + 16 * MM;   // [B,H,D,S]
    short* ao     = ws + 20 * MM;

    prep<<<dim3(3072), 256, 0, stream>>>(x, xb, Wq, Wk, Wv, Wo,
                                         wt_qkv, wt_qkv + MM, wt_qkv + 2 * MM, wot);
    gemm_bf16<<<dim3(MDIM / 128, HID / 128, 3), 512, 0, stream>>>(
        xb, wt_qkv, bq, bk, bv, fc, fs, qt, nullptr, 0);
    attn_fwd<<<dim3(16, BDIM * HDIM), 512, 0, stream>>>(qt, ktb, vtb, ao);
    gemm_bf16<<<dim3(MDIM / 128, HID / 128, 1), 512, 0, stream>>>(
        ao, wot, bo, bo, bo, fc, fs, nullptr, out, 3);
}

// Round 22
// 100.984 us; speedup vs baseline: 1.2184x; 1.0194x over previous
//
#include <hip/hip_runtime.h>
#include <hip/hip_bf16.h>

#define BDIM 2
#define SDIM 2048
#define HDIM 16
#define DDIM 64
#define HID  1024
#define MDIM (BDIM * SDIM)  // 4096

typedef __attribute__((ext_vector_type(8))) short short8;
typedef __attribute__((ext_vector_type(4))) short short4v;
typedef __attribute__((ext_vector_type(4))) float f32x4;
typedef __attribute__((ext_vector_type(2))) unsigned int uint2v;

__device__ __forceinline__ float bf2f(short u) {
    union { unsigned int i; float f; } x;
    x.i = ((unsigned int)(unsigned short)u) << 16;
    return x.f;
}
__device__ __forceinline__ short f2bf(float f) {
    union { float f; unsigned int i; } x; x.f = f;
    unsigned int r = x.i + 0x7fffu + ((x.i >> 16) & 1u);
    return (short)(r >> 16);
}
__device__ __forceinline__ unsigned int cvtpk_bf16(float lo, float hi) {
    unsigned int r;
    asm("v_cvt_pk_bf16_f32 %0, %1, %2" : "=v"(r) : "v"(lo), "v"(hi));
    return r;
}
// swizzled short-index into a [rows][64 shorts] tile; c8 = 16B chunk (0..7)
__device__ __forceinline__ int swz(int row, int c8) {
    return row * 64 + ((c8 ^ (row & 7)) << 3);
}

// ------- merged prep: cvt x->bf16 (blocks 0..2047) + weight transpose -------
__global__ __launch_bounds__(256) void prep(
    const float* __restrict__ x, short* __restrict__ xb,
    const float* __restrict__ w0, const float* __restrict__ w1,
    const float* __restrict__ w2, const float* __restrict__ w3,
    short* __restrict__ o0, short* __restrict__ o1,
    short* __restrict__ o2, short* __restrict__ o3)
{
    int bid = blockIdx.x;
    if (bid < 2048) {
        int i = (bid * 256 + threadIdx.x) * 8;
        float4 a = *(const float4*)(x + i);
        float4 b = *(const float4*)(x + i + 4);
        short8 v;
        v[0] = f2bf(a.x); v[1] = f2bf(a.y); v[2] = f2bf(a.z); v[3] = f2bf(a.w);
        v[4] = f2bf(b.x); v[5] = f2bf(b.y); v[6] = f2bf(b.z); v[7] = f2bf(b.w);
        *(short8*)(xb + i) = v;
        return;
    }
    __shared__ float t[64][65];
    int b = bid - 2048;
    int z = b >> 8, rem = b & 255;
    const float* src; short* dst;
    if (z == 0)      { src = w0; dst = o0; }
    else if (z == 1) { src = w1; dst = o1; }
    else if (z == 2) { src = w2; dst = o2; }
    else             { src = w3; dst = o3; }
    int r0 = (rem >> 4) * 64, c0 = (rem & 15) * 64;
    int rd_r = threadIdx.x >> 4, rd_c = (threadIdx.x & 15) * 4;
    #pragma unroll
    for (int it = 0; it < 4; it++) {
        int rr = rd_r + it * 16;
        float4 v = *(const float4*)(src + (size_t)(r0 + rr) * HID + c0 + rd_c);
        t[rr][rd_c + 0] = v.x; t[rr][rd_c + 1] = v.y;
        t[rr][rd_c + 2] = v.z; t[rr][rd_c + 3] = v.w;
    }
    __syncthreads();
    int or_ = threadIdx.x >> 3, oc8 = (threadIdx.x & 7) * 8;
    #pragma unroll
    for (int half = 0; half < 2; half++) {
        int dr = or_ + half * 32;
        short8 v;
        #pragma unroll
        for (int i = 0; i < 8; i++) v[i] = f2bf(t[oc8 + i][dr]);
        *(short8*)(dst + (size_t)(c0 + dr) * HID + r0 + oc8) = v;
    }
}

// ------- GEMM, 8-wave 128x128 tile, 2-phase dbuf reg-staging (R20 best) -------
__global__ __launch_bounds__(512) void gemm_bf16(
    const short* __restrict__ X,
    const short* __restrict__ Wt0,
    const float* __restrict__ b0, const float* __restrict__ b1, const float* __restrict__ b2,
    const float* __restrict__ cosb, const float* __restrict__ sinb,
    short* __restrict__ out0, float* __restrict__ outf,
    int modeBase)
{
    __shared__ __align__(16) short Asm[2][128 * 32];   // 16 KB
    __shared__ __align__(16) short Bsm[2][128 * 32];   // 16 KB
    int z = blockIdx.z;
    int mode = modeBase + z;
    const short* Wt = Wt0 + (size_t)z * HID * HID;
    const float* bias = (z == 0) ? b0 : (z == 1) ? b1 : b2;
    short* outp = out0 + (size_t)z * MDIM * HID;

    int tid = threadIdx.x;
    int lane = tid & 63, wave = tid >> 6;   // wave 0..7
    int wr = wave >> 2, wc = wave & 3;      // 2 x 4 wave grid
    int m0 = blockIdx.x * 128, n0 = blockIdx.y * 128;
    int sr = tid >> 2, sc = (tid & 3) * 8;  // sr 0..127: full tile coverage
    int lr = lane & 15, lg = lane >> 4;

    const short* ax = X  + (size_t)(m0 + sr) * HID + sc;
    const short* bx = Wt + (size_t)(n0 + sr) * HID + sc;
    int csw = ((tid & 3) ^ ((sr >> 1) & 3)) * 8;
    int wA  = sr * 32 + csw;
    int rdsw = (lg ^ ((lr >> 1) & 3)) * 8;

    f32x4 acc[4][2] = {};
    constexpr int NK = HID / 32;  // 32 K-steps

    short8 a0, b0v;
    a0  = *(const short8*)(ax);
    b0v = *(const short8*)(bx);
    *(short8*)(Asm[0] + wA) = a0;
    *(short8*)(Bsm[0] + wA) = b0v;
    a0  = *(const short8*)(ax + 32);
    b0v = *(const short8*)(bx + 32);

    int cur = 0;
    for (int ki = 0; ki < NK; ki++) {
        __syncthreads();
        if (ki + 1 < NK) {
            *(short8*)(Asm[cur ^ 1] + wA) = a0;
            *(short8*)(Bsm[cur ^ 1] + wA) = b0v;
        }
        if (ki + 2 < NK) {
            int k0 = (ki + 2) * 32;
            a0  = *(const short8*)(ax + k0);
            b0v = *(const short8*)(bx + k0);
        }
        short8 af[4], bfr[2];
        #pragma unroll
        for (int m = 0; m < 4; m++)
            af[m] = *(const short8*)(Asm[cur] + (wr * 64 + m * 16 + lr) * 32 + rdsw);
        #pragma unroll
        for (int n = 0; n < 2; n++)
            bfr[n] = *(const short8*)(Bsm[cur] + (wc * 32 + n * 16 + lr) * 32 + rdsw);
        __builtin_amdgcn_s_setprio(1);
        #pragma unroll
        for (int m = 0; m < 4; m++)
            #pragma unroll
            for (int n = 0; n < 2; n++)
                acc[m][n] = __builtin_amdgcn_mfma_f32_16x16x32_bf16(af[m], bfr[n], acc[m][n], 0, 0, 0);
        __builtin_amdgcn_s_setprio(0);
        cur ^= 1;
    }

    #pragma unroll
    for (int m = 0; m < 4; m++) {
        #pragma unroll
        for (int n = 0; n < 2; n++) {
            int gr0 = m0 + wr * 64 + m * 16 + lg * 4;
            int gc  = n0 + wc * 32 + n * 16 + lr;
            if (mode == 3) {
                #pragma unroll
                for (int j = 0; j < 4; j++)
                    outf[(size_t)(gr0 + j) * HID + gc] = acc[m][n][j] + bias[gc];
            } else if (mode == 2) {
                int bb = gr0 >> 11, s0 = gr0 & (SDIM - 1);
                int h = gc >> 6, dd = gc & 63;
                short4v pk;
                #pragma unroll
                for (int j = 0; j < 4; j++) pk[j] = f2bf(acc[m][n][j] + bias[gc]);
                *(short4v*)(outp + ((size_t)((bb * HDIM + h) * DDIM + dd)) * SDIM + s0) = pk;
            } else {
                #pragma unroll
                for (int j = 0; j < 4; j++) {
                    int gr = gr0 + j;
                    int bb = gr >> 11, s = gr & (SDIM - 1);
                    int h = gc >> 6, dd = gc & 63;
                    float v = acc[m][n][j] + bias[gc];
                    float p  = __shfl_xor(v, 1);
                    float cc = cosb[s * 32 + (dd >> 1)];
                    float ss = sinb[s * 32 + (dd >> 1)];
                    v = (dd & 1) ? (p * ss + v * cc) : (v * cc - p * ss);
                    outp[((size_t)((bb * HDIM + h) * SDIM + s)) * DDIM + dd] = f2bf(v);
                }
            }
        }
    }
}

// ------- causal flash attention: 8-wave blocks, maxless softmax (R20 best) ---
__global__ __launch_bounds__(512) void attn_fwd(
    const short* __restrict__ Q,
    const short* __restrict__ K,
    const short* __restrict__ Vt,
    short* __restrict__ O)
{
    __shared__ __align__(16) short Ks0[64 * 64], Ks1[64 * 64];
    __shared__ __align__(16) short Vs0[64 * 64], Vs1[64 * 64];
    __shared__ __align__(16) short Ps[8][16 * 64];
    int bx = blockIdx.x;                  // 0..15
    int qA = bx, qB = 31 - bx;            // qA < qB
    int bh = blockIdx.y;
    int tid = threadIdx.x;
    int lane = tid & 63, wave = tid >> 6;  // wave 0..7
    int wv = wave & 3, grp = wave >> 2;    // grp 0 -> qB, grp 1 -> qA
    int lr = lane & 15, lg = lane >> 4;
    const short* qbase  = Q  + ((size_t)bh * SDIM) * DDIM;
    const short* kbase  = K  + ((size_t)bh * SDIM) * DDIM;
    const short* vtbase = Vt + ((size_t)bh * DDIM) * SDIM;

    const float SCALE = 0.125f * 1.44269504088896340736f;  // 1/sqrt(64) * log2(e)

    int qt_own = grp ? qA : qB;
    int qrow = qt_own * 64 + wv * 16 + lr;

    short8 qf[2];
    #pragma unroll
    for (int ks = 0; ks < 2; ks++) {
        short8 a = *(const short8*)(qbase + (size_t)qrow * DDIM + ks * 32 + lg * 8);
        short8 ra;
        #pragma unroll
        for (int i = 0; i < 8; i++) ra[i] = f2bf(bf2f(a[i]) * SCALE);
        qf[ks] = ra;
    }

    f32x4 lacc = {0.f, 0.f, 0.f, 0.f};
    f32x4 oacc[4] = {};

    int sr_ = tid >> 3, sc8 = tid & 7;
    int kw = swz(sr_, sc8);
    int fo[8];
    #pragma unroll
    for (int ks = 0; ks < 2; ks++)
        #pragma unroll
        for (int n = 0; n < 4; n++) fo[ks * 4 + n] = swz(n * 16 + lr, ks * 4 + lg);
    int po[2] = { swz(lr, lg), swz(lr, 4 + lg) };
    int pw[4];
    #pragma unroll
    for (int n = 0; n < 4; n++)
        pw[n] = lr * 64 + (((n * 2 + (lg >> 1)) ^ (lr & 7)) << 3) + (lg & 1) * 4;

    int nt = qB + 1;  // >= 17

    short8 kreg, vreg;
    kreg = *(const short8*)(kbase + (size_t)sr_ * DDIM + sc8 * 8);
    vreg = *(const short8*)(vtbase + (size_t)sr_ * SDIM + sc8 * 8);
    *(short8*)(Ks0 + kw) = kreg;
    *(short8*)(Vs0 + kw) = vreg;
    kreg = *(const short8*)(kbase + (size_t)(64 + sr_) * DDIM + sc8 * 8);
    vreg = *(const short8*)(vtbase + (size_t)sr_ * SDIM + 64 + sc8 * 8);
    const short* kpre = kbase + (size_t)(128 + sr_) * DDIM + sc8 * 8;
    const short* vpre = vtbase + (size_t)sr_ * SDIM + 128 + sc8 * 8;

    auto pv = [&](f32x4 (&st)[4], bool diag, int kt, short* VsC) {
        if (diag) {
            #pragma unroll
            for (int n = 0; n < 4; n++)
                #pragma unroll
                for (int j = 0; j < 4; j++) {
                    int k = kt * 64 + n * 16 + lg * 4 + j;
                    if (k > qrow) st[n][j] = -1e30f;
                }
        }
        #pragma unroll
        for (int n = 0; n < 4; n++) {
            #pragma unroll
            for (int j = 0; j < 4; j++) st[n][j] = exp2f(st[n][j]);
            lacc[n] += (st[n][0] + st[n][1]) + (st[n][2] + st[n][3]);
        }
        #pragma unroll
        for (int n = 0; n < 4; n++) {
            uint2v pk;
            pk[0] = cvtpk_bf16(st[n][0], st[n][1]);
            pk[1] = cvtpk_bf16(st[n][2], st[n][3]);
            *(uint2v*)(Ps[wave] + pw[n]) = pk;
        }
        __builtin_amdgcn_s_setprio(1);
        #pragma unroll
        for (int ks = 0; ks < 2; ks++) {
            short8 pf = *(const short8*)(Ps[wave] + po[ks]);
            #pragma unroll
            for (int n = 0; n < 4; n++) {
                short8 vf = *(const short8*)(VsC + fo[ks * 4 + n]);
                oacc[n] = __builtin_amdgcn_mfma_f32_16x16x32_bf16(pf, vf, oacc[n], 0, 0, 0);
            }
        }
        __builtin_amdgcn_s_setprio(0);
    };

    auto tile = [&](int kt, short* KsC, short* VsC, short* KsN, short* VsN) {
        __syncthreads();
        if (kt + 1 < nt) {
            *(short8*)(KsN + kw) = kreg;
            *(short8*)(VsN + kw) = vreg;
        }
        if (kt + 2 < nt) {
            kreg = *(const short8*)(kpre);
            vreg = *(const short8*)(vpre);
        }
        kpre += 64 * DDIM;
        vpre += 64;

        bool act = grp ? (kt <= qA) : true;
        if (act) {
            f32x4 st[4] = {};
            __builtin_amdgcn_s_setprio(1);
            #pragma unroll
            for (int ks = 0; ks < 2; ks++) {
                short8 kf[4];
                #pragma unroll
                for (int n = 0; n < 4; n++) kf[n] = *(const short8*)(KsC + fo[ks * 4 + n]);
                #pragma unroll
                for (int n = 0; n < 4; n++)
                    st[n] = __builtin_amdgcn_mfma_f32_16x16x32_bf16(kf[n], qf[ks], st[n], 0, 0, 0);
            }
            __builtin_amdgcn_s_setprio(0);
            pv(st, kt == qt_own, kt, VsC);
        }
    };

    for (int kt = 0; kt < nt; kt += 2) {
        tile(kt, Ks0, Vs0, Ks1, Vs1);
        if (kt + 1 < nt) tile(kt + 1, Ks1, Vs1, Ks0, Vs0);
    }

    float l = (lacc[0] + lacc[1]) + (lacc[2] + lacc[3]);
    l += __shfl_xor(l, 16);
    l += __shfl_xor(l, 32);
    int b = bh >> 4, h = bh & 15;
    float linv[4];
    #pragma unroll
    for (int j = 0; j < 4; j++)
        linv[j] = 1.f / __int_as_float(__builtin_amdgcn_ds_bpermute((lg * 4 + j) * 4, __float_as_int(l)));
    #pragma unroll
    for (int n = 0; n < 4; n++)
        #pragma unroll
        for (int j = 0; j < 4; j++) {
            int s = qt_own * 64 + wv * 16 + lg * 4 + j;
            int dd = n * 16 + lr;
            O[(((size_t)(b * SDIM + s) * HDIM) + h) * DDIM + dd] = f2bf(oacc[n][j] * linv[j]);
        }
}

extern "C" void kernel_launch(void* const* d_in, const int* in_sizes, int n_in,
                              void* d_out, int out_size, void* d_ws, size_t ws_size,
                              hipStream_t stream) {
    const float* x  = (const float*)d_in[0];
    const float* Wq = (const float*)d_in[1];
    const float* bq = (const float*)d_in[2];
    const float* Wk = (const float*)d_in[3];
    const float* bk = (const float*)d_in[4];
    const float* Wv = (const float*)d_in[5];
    const float* bv = (const float*)d_in[6];
    const float* Wo = (const float*)d_in[7];
    const float* bo = (const float*)d_in[8];
    const float* fc = (const float*)d_in[10];
    const float* fs = (const float*)d_in[11];
    float* out = (float*)d_out;
    short* ws  = (short*)d_ws;

    const size_t MM = (size_t)HID * HID;
    short* xb     = ws;
    short* wt_qkv = ws + 4 * MM;
    short* wot    = ws + 7 * MM;
    short* qt     = ws + 8 * MM;
    short* ktb    = ws + 12 * MM;
    short* vtb    = ws + 16 * MM;   // [B,H,D,S]
    short* ao     = ws + 20 * MM;

    prep<<<dim3(3072), 256, 0, stream>>>(x, xb, Wq, Wk, Wv, Wo,
                                         wt_qkv, wt_qkv + MM, wt_qkv + 2 * MM, wot);
    gemm_bf16<<<dim3(MDIM / 128, HID / 128, 3), 512, 0, stream>>>(
        xb, wt_qkv, bq, bk, bv, fc, fs, qt, nullptr, 0);
    attn_fwd<<<dim3(16, BDIM * HDIM), 512, 0, stream>>>(qt, ktb, vtb, ao);
    gemm_bf16<<<dim3(MDIM / 128, HID / 128, 1), 512, 0, stream>>>(
        ao, wot, bo, bo, bo, fc, fs, nullptr, out, 3);
}